// Round 1
// baseline (273.303 us; speedup 1.0000x reference)
//
#include <hip/hip_runtime.h>
#include <stdint.h>

#define N_  32
#define C_  128
#define H_  56
#define W_  56
#define HW_ 3136
#define P_  128
#define PSPLIT 2
#define PB  (P_/PSPLIT)   // 64 output channels per block

// Workspace layout (bytes):
//   abits : N*HW*16            = 1,605,632   (uint4 per pixel: 128 sign bits)
//   wbits : P*9*4*4            = 18,432      (uint4 per (p,tap))
//   A     : P*4                = 512
//   B     : P*4                = 512
#define ABITS_BYTES (N_*HW_*16)
#define WBITS_BYTES (P_*9*16)

// ---------------- pack x into sign bits (bit c=1 <=> x>=0 <=> +1) -------------
__global__ __launch_bounds__(256) void pack_x_kernel(const float* __restrict__ x,
                                                     uint4* __restrict__ abits) {
    int i = blockIdx.x * 256 + threadIdx.x;      // over N*H*(W/4) = 25088
    if (i >= N_*H_*14) return;
    int n = i / (H_*14);
    int r = i % (H_*14);
    int h = r / 14, q = r % 14;
    const float* px = x + (size_t)n*C_*HW_ + h*W_ + q*4;
    uint32_t wb[4][4] = {};
    #pragma unroll 16
    for (int c = 0; c < C_; ++c) {
        float4 v = *(const float4*)(px + (size_t)c*HW_);
        uint32_t bit = 1u << (c & 31);
        int j = c >> 5;
        if (v.x >= 0.f) wb[0][j] |= bit;
        if (v.y >= 0.f) wb[1][j] |= bit;
        if (v.z >= 0.f) wb[2][j] |= bit;
        if (v.w >= 0.f) wb[3][j] |= bit;
    }
    uint4* dst = abits + (n*HW_ + h*W_ + q*4);
    dst[0] = make_uint4(wb[0][0], wb[0][1], wb[0][2], wb[0][3]);
    dst[1] = make_uint4(wb[1][0], wb[1][1], wb[1][2], wb[1][3]);
    dst[2] = make_uint4(wb[2][0], wb[2][1], wb[2][2], wb[2][3]);
    dst[3] = make_uint4(wb[3][0], wb[3][1], wb[3][2], wb[3][3]);
}

// -------- pack weights into sign bits + fold bias/BN into per-p A,B ----------
__global__ __launch_bounds__(256) void pack_w_kernel(const float* __restrict__ weight,
        const float* __restrict__ bias, const float* __restrict__ gamma,
        const float* __restrict__ beta, const float* __restrict__ mean,
        const float* __restrict__ var,
        uint32_t* __restrict__ wbits, float* __restrict__ A, float* __restrict__ B) {
    int gid = blockIdx.x * 256 + threadIdx.x;
    if (gid < P_*9) {
        int p = gid / 9, t = gid % 9;            // t = kh*3+kw
        const float* pw = weight + (size_t)p*C_*9 + t;
        uint32_t w0=0, w1=0, w2=0, w3=0;
        #pragma unroll 16
        for (int c = 0; c < C_; ++c) {
            float v = pw[(size_t)c*9];
            uint32_t bit = 1u << (c & 31);
            if (c < 32)       { if (v >= 0.f) w0 |= bit; }
            else if (c < 64)  { if (v >= 0.f) w1 |= bit; }
            else if (c < 96)  { if (v >= 0.f) w2 |= bit; }
            else              { if (v >= 0.f) w3 |= bit; }
        }
        wbits[gid*4+0] = w0; wbits[gid*4+1] = w1;
        wbits[gid*4+2] = w2; wbits[gid*4+3] = w3;
    }
    if (gid < P_) {
        float inv = gamma[gid] * rsqrtf(var[gid] + 1e-5f);
        A[gid] = inv;
        B[gid] = bias[gid]*inv + beta[gid] - mean[gid]*inv;
    }
}

// ---------------- binary conv + BN + residual --------------------------------
__global__ __launch_bounds__(256) void bconv_kernel(
        const uint4* __restrict__ abits, const uint32_t* __restrict__ wbits,
        const float* __restrict__ A, const float* __restrict__ B,
        const float* __restrict__ x, float* __restrict__ out) {
    __shared__ uint32_t sw[PB*36];       // 9 KB: PB channels x 9 taps x 4 words
    __shared__ uint32_t scorr[9*PB];     // padding correction per border class
    __shared__ float sA[PB], sB[PB];

    int tid = threadIdx.x;
    int pixBlock = blockIdx.x >> 1;
    int pbase = (blockIdx.x & 1) * PB;

    for (int k = tid; k < PB*36; k += 256) sw[k] = wbits[pbase*36 + k];
    if (tid < PB) { sA[tid] = A[pbase+tid]; sB[tid] = B[pbase+tid]; }
    __syncthreads();

    // corr[cls][p] = sum over invalid taps of popc(w bits)
    for (int k = tid; k < 9*PB; k += 256) {
        int cls = k / PB, pp = k % PB;
        int chc = cls / 3, cwc = cls % 3;
        uint32_t s = 0;
        #pragma unroll
        for (int t = 0; t < 9; ++t) {
            int kh = t/3, kw = t%3;      // 0,1,2 ~ -1,0,+1
            bool inval = (chc==0 && kh==0) || (chc==2 && kh==2) ||
                         (cwc==0 && kw==0) || (cwc==2 && kw==2);
            if (inval) {
                s += __popc(sw[pp*36+t*4+0]) + __popc(sw[pp*36+t*4+1])
                   + __popc(sw[pp*36+t*4+2]) + __popc(sw[pp*36+t*4+3]);
            }
        }
        scorr[k] = s;
    }
    __syncthreads();

    int i = pixBlock*256 + tid;          // pixel id, grid sized exactly
    int n = i / HW_;
    int r = i % HW_;
    int h = r / W_;
    int w = r % W_;

    uint32_t a[9][4];
    int V = 0;
    #pragma unroll
    for (int t = 0; t < 9; ++t) {
        int hh = h + t/3 - 1, ww = w + t%3 - 1;
        bool valid = ((unsigned)hh < H_) && ((unsigned)ww < W_);
        if (valid) {
            uint4 v = abits[n*HW_ + hh*W_ + ww];
            a[t][0]=v.x; a[t][1]=v.y; a[t][2]=v.z; a[t][3]=v.w;
            ++V;
        } else {
            a[t][0]=0; a[t][1]=0; a[t][2]=0; a[t][3]=0;
        }
    }
    int chc = (h==0) ? 0 : (h==H_-1 ? 2 : 1);
    int cwc = (w==0) ? 0 : (w==W_-1 ? 2 : 1);
    const uint32_t* corr_row = &scorr[(chc*3+cwc)*PB];

    const float* xr = x   + (size_t)(n*P_ + pbase)*HW_ + r;
    float*       po = out + (size_t)(n*P_ + pbase)*HW_ + r;
    int base = 128*V;

    for (int p = 0; p < PB; ++p) {
        const uint32_t* wp = &sw[p*36];
        int cnt = 0;
        #pragma unroll
        for (int t = 0; t < 9; ++t) {
            cnt += __popc(a[t][0] ^ wp[t*4+0]);
            cnt += __popc(a[t][1] ^ wp[t*4+1]);
            cnt += __popc(a[t][2] ^ wp[t*4+2]);
            cnt += __popc(a[t][3] ^ wp[t*4+3]);
        }
        int dot = base - 2*(cnt - (int)corr_row[p]);
        float y = (float)dot * sA[p] + sB[p] + xr[(size_t)p*HW_];
        po[(size_t)p*HW_] = y;
    }
}

extern "C" void kernel_launch(void* const* d_in, const int* in_sizes, int n_in,
                              void* d_out, int out_size, void* d_ws, size_t ws_size,
                              hipStream_t stream) {
    const float* x      = (const float*)d_in[0];
    const float* weight = (const float*)d_in[1];
    const float* bias   = (const float*)d_in[2];
    const float* gamma  = (const float*)d_in[3];
    const float* beta   = (const float*)d_in[4];
    const float* mean   = (const float*)d_in[5];
    const float* var    = (const float*)d_in[6];
    float* out = (float*)d_out;

    uint8_t* ws = (uint8_t*)d_ws;
    uint4*    abits = (uint4*)ws;
    uint32_t* wbits = (uint32_t*)(ws + ABITS_BYTES);
    float*    A     = (float*)(ws + ABITS_BYTES + WBITS_BYTES);
    float*    B     = A + P_;

    pack_x_kernel<<<98, 256, 0, stream>>>(x, abits);
    pack_w_kernel<<<5, 256, 0, stream>>>(weight, bias, gamma, beta, mean, var, wbits, A, B);
    bconv_kernel<<<784, 256, 0, stream>>>(abits, wbits, A, B, x, out);
}

// Round 2
// 189.445 us; speedup vs baseline: 1.4426x; 1.4426x over previous
//
#include <hip/hip_runtime.h>
#include <stdint.h>

#define N_  32
#define C_  128
#define H_  56
#define W_  56
#define HW_ 3136
#define P_  128
#define PB  64
#define NPIX (N_*HW_)           // 100352

// Workspace layout (bytes):
//   abits : NPIX*16      = 1,605,632
//   wbits : P*9*16       = 18,432
//   A     : P*4  (gamma*rsqrt(var+eps))
//   B0    : P*4  (bias*inv + beta - mean*inv)
//   negA  : P*4  (-2*A)
//   K     : 9*P*4 (per border-class fused constant)
#define ABITS_BYTES (NPIX*16)
#define WBITS_BYTES (P_*9*16)

// ---------------- pack x into sign bits: one thread per pixel ----------------
__global__ __launch_bounds__(64) void pack_x_kernel(const float* __restrict__ x,
                                                    uint4* __restrict__ abits) {
    int i = blockIdx.x * 64 + threadIdx.x;   // grid exact: NPIX/64 = 1568
    int n = i / HW_;
    int r = i % HW_;
    const float* px = x + (size_t)n * C_ * HW_ + r;
    uint32_t w0 = 0, w1 = 0, w2 = 0, w3 = 0;
    #pragma unroll
    for (int c = 0; c < 32; ++c) if (px[(size_t)c        * HW_] >= 0.f) w0 |= 1u << c;
    #pragma unroll
    for (int c = 0; c < 32; ++c) if (px[(size_t)(c + 32) * HW_] >= 0.f) w1 |= 1u << c;
    #pragma unroll
    for (int c = 0; c < 32; ++c) if (px[(size_t)(c + 64) * HW_] >= 0.f) w2 |= 1u << c;
    #pragma unroll
    for (int c = 0; c < 32; ++c) if (px[(size_t)(c + 96) * HW_] >= 0.f) w3 |= 1u << c;
    abits[i] = make_uint4(w0, w1, w2, w3);
}

// -------- pack weights to sign bits + fold bias/BN into per-p A, B0 ----------
__global__ __launch_bounds__(256) void pack_w_kernel(const float* __restrict__ weight,
        const float* __restrict__ bias, const float* __restrict__ gamma,
        const float* __restrict__ beta, const float* __restrict__ mean,
        const float* __restrict__ var,
        uint32_t* __restrict__ wbits, float* __restrict__ A, float* __restrict__ B0) {
    int gid = blockIdx.x * 256 + threadIdx.x;
    if (gid < P_ * 9) {
        int p = gid / 9, t = gid % 9;        // t = kh*3+kw
        const float* pw = weight + (size_t)p * C_ * 9 + t;
        uint32_t w[4] = {0, 0, 0, 0};
        #pragma unroll 16
        for (int c = 0; c < C_; ++c) {
            if (pw[(size_t)c * 9] >= 0.f) w[c >> 5] |= 1u << (c & 31);
        }
        wbits[gid*4+0] = w[0]; wbits[gid*4+1] = w[1];
        wbits[gid*4+2] = w[2]; wbits[gid*4+3] = w[3];
    }
    if (gid < P_) {
        float inv = gamma[gid] * rsqrtf(var[gid] + 1e-5f);
        A[gid]  = inv;
        B0[gid] = bias[gid] * inv + beta[gid] - mean[gid] * inv;
    }
}

// -------- fused border-class table: K[cls][p], negA[p] -----------------------
__global__ __launch_bounds__(256) void ktab_kernel(const uint32_t* __restrict__ wbits,
        const float* __restrict__ A, const float* __restrict__ B0,
        float* __restrict__ K, float* __restrict__ negA) {
    int gid = blockIdx.x * 256 + threadIdx.x;
    if (gid < 9 * P_) {
        int cls = gid / P_, p = gid % P_;
        int chc = cls / 3, cwc = cls % 3;
        int corr = 0;
        #pragma unroll
        for (int t = 0; t < 9; ++t) {
            int kh = t / 3, kw = t % 3;
            bool inval = (chc == 0 && kh == 0) || (chc == 2 && kh == 2) ||
                         (cwc == 0 && kw == 0) || (cwc == 2 && kw == 2);
            if (inval) {
                corr += __popc(wbits[p*36 + t*4 + 0]) + __popc(wbits[p*36 + t*4 + 1])
                      + __popc(wbits[p*36 + t*4 + 2]) + __popc(wbits[p*36 + t*4 + 3]);
            }
        }
        int V = ((chc == 1) ? 3 : 2) * ((cwc == 1) ? 3 : 2);
        K[gid] = (128.f * (float)V + 2.f * (float)corr) * A[p] + B0[p];
    }
    if (gid < P_) negA[gid] = -2.f * A[gid];
}

// ---------------- binary conv + BN + residual --------------------------------
__global__ __launch_bounds__(256) void bconv_kernel(
        const uint4* __restrict__ abits, const uint4* __restrict__ wbits4,
        const float* __restrict__ Kg, const float* __restrict__ negAg,
        const float* __restrict__ x, float* __restrict__ out) {
    __shared__ uint4  sw4[PB * 9];       // 9216 B, 16B-aligned per p
    __shared__ float  sK[9 * PB];        // 2304 B
    __shared__ float  sNegA[PB];

    int tid   = threadIdx.x;
    int pbase = (blockIdx.x & 1) * PB;
    int i     = (blockIdx.x >> 1) * 256 + tid;   // pixel id, grid exact

    for (int k = tid; k < PB * 9; k += 256) sw4[k] = wbits4[pbase * 9 + k];
    for (int k = tid; k < 9 * PB; k += 256)
        sK[k] = Kg[(k / PB) * P_ + pbase + (k % PB)];
    if (tid < PB) sNegA[tid] = negAg[pbase + tid];
    __syncthreads();

    int n = i / HW_;
    int r = i % HW_;
    int h = r / W_;
    int w = r % W_;

    uint4 a[9];
    #pragma unroll
    for (int t = 0; t < 9; ++t) {
        int hh = h + t / 3 - 1, ww = w + t % 3 - 1;
        bool valid = ((unsigned)hh < H_) && ((unsigned)ww < W_);
        if (valid) a[t] = abits[n * HW_ + hh * W_ + ww];
        else       a[t] = make_uint4(0u, 0u, 0u, 0u);
    }
    int cls = ((h == 0) ? 0 : (h == H_ - 1 ? 2 : 1)) * 3
            + ((w == 0) ? 0 : (w == W_ - 1 ? 2 : 1));
    const float* Kr = &sK[cls * PB];
    const float* xr = x   + ((size_t)n * P_ + pbase) * HW_ + r;
    float*       po = out + ((size_t)n * P_ + pbase) * HW_ + r;

    for (int pc = 0; pc < PB; pc += 8) {
        float xv[8];
        #pragma unroll
        for (int j = 0; j < 8; ++j) xv[j] = xr[(size_t)(pc + j) * HW_];
        #pragma unroll
        for (int j = 0; j < 8; ++j) {
            const uint4* wp = &sw4[(pc + j) * 9];
            int cnt = 0;
            #pragma unroll
            for (int t = 0; t < 9; ++t) {
                uint4 wv = wp[t];
                cnt += __popc(a[t].x ^ wv.x) + __popc(a[t].y ^ wv.y)
                     + __popc(a[t].z ^ wv.z) + __popc(a[t].w ^ wv.w);
            }
            po[(size_t)(pc + j) * HW_] =
                fmaf((float)cnt, sNegA[pc + j], Kr[pc + j]) + xv[j];
        }
    }
}

extern "C" void kernel_launch(void* const* d_in, const int* in_sizes, int n_in,
                              void* d_out, int out_size, void* d_ws, size_t ws_size,
                              hipStream_t stream) {
    const float* x      = (const float*)d_in[0];
    const float* weight = (const float*)d_in[1];
    const float* bias   = (const float*)d_in[2];
    const float* gamma  = (const float*)d_in[3];
    const float* beta   = (const float*)d_in[4];
    const float* mean   = (const float*)d_in[5];
    const float* var    = (const float*)d_in[6];
    float* out = (float*)d_out;

    uint8_t*  ws    = (uint8_t*)d_ws;
    uint4*    abits = (uint4*)ws;
    uint32_t* wbits = (uint32_t*)(ws + ABITS_BYTES);
    float*    A     = (float*)(ws + ABITS_BYTES + WBITS_BYTES);
    float*    B0    = A + P_;
    float*    negA  = B0 + P_;
    float*    K     = negA + P_;

    pack_x_kernel<<<NPIX / 64, 64, 0, stream>>>(x, abits);
    pack_w_kernel<<<5, 256, 0, stream>>>(weight, bias, gamma, beta, mean, var, wbits, A, B0);
    ktab_kernel<<<5, 256, 0, stream>>>(wbits, A, B0, K, negA);
    bconv_kernel<<<(NPIX / 256) * 2, 256, 0, stream>>>(abits, (const uint4*)wbits, K, negA, x, out);
}